// Round 7
// baseline (608.561 us; speedup 1.0000x reference)
//
#include <hip/hip_runtime.h>
#include <hip/hip_bf16.h>

#define IN_DIM 768
#define HID 128
#define NC 7
#define GSH 13   // src-group = src >> 13 (8192 rows = 2 MB of G per group)

typedef __attribute__((ext_vector_type(8))) short bf16x8;
typedef __attribute__((ext_vector_type(4))) float f32x4;

__device__ __forceinline__ ushort f2bf(float f) {
  uint u = __float_as_uint(f);
  u += 0x7fffu + ((u >> 16) & 1u);   // round-to-nearest-even
  return (ushort)(u >> 16);
}
__device__ __forceinline__ float lof(uint v) { return __uint_as_float(v << 16); }
__device__ __forceinline__ float hif(uint v) { return __uint_as_float(v & 0xffff0000u); }
__device__ __forceinline__ uint cvtpk(float lo, float hi) {
  uint r;
  asm("v_cvt_pk_bf16_f32 %0, %1, %2" : "=v"(r) : "v"(lo), "v"(hi));
  return r;
}

// ---------------- CSR build (group-sorted rows) ----------------

// histogram per (dst, src-group); pos[e] = arrival order within (dst,group)
__global__ __launch_bounds__(256) void k_count(const int* __restrict__ src,
                                               const int* __restrict__ dst,
                                               int* __restrict__ cnt2,
                                               int* __restrict__ pos, int E, int NG) {
  int e0 = (blockIdx.x * 256 + threadIdx.x) * 4;
  if (e0 + 4 <= E) {
    int4 s4 = *(const int4*)&src[e0];
    int4 d4 = *(const int4*)&dst[e0];
    int4 p;
    p.x = atomicAdd(&cnt2[d4.x * NG + (s4.x >> GSH)], 1);
    p.y = atomicAdd(&cnt2[d4.y * NG + (s4.y >> GSH)], 1);
    p.z = atomicAdd(&cnt2[d4.z * NG + (s4.z >> GSH)], 1);
    p.w = atomicAdd(&cnt2[d4.w * NG + (s4.w >> GSH)], 1);
    *(int4*)&pos[e0] = p;
  } else {
    for (int e = e0; e < E; ++e)
      pos[e] = atomicAdd(&cnt2[dst[e] * NG + (src[e] >> GSH)], 1);
  }
}

// in-place exclusive scan of cnt2 along groups per node; cnt[n] = total degree
__global__ __launch_bounds__(256) void k_rowscan(int* __restrict__ cnt2,
                                                 int* __restrict__ cnt, int N, int NG) {
  int n = blockIdx.x * 256 + threadIdx.x;
  if (n >= N) return;
  int s = 0;
  for (int g = 0; g < NG; ++g) {
    int b = cnt2[n * NG + g];
    cnt2[n * NG + g] = s;
    s += b;
  }
  cnt[n] = s;
}

__device__ __forceinline__ int pad4(int c) { return (c + 3) & ~3; }

__global__ void k_scan_partial(const int* __restrict__ cnt, int* __restrict__ partials, int N) {
  __shared__ int sm[256];
  int b = blockIdx.x, t = threadIdx.x;
  int base = b * 1024 + t * 4;
  int s = 0;
  #pragma unroll
  for (int j = 0; j < 4; ++j) if (base + j < N) s += pad4(cnt[base + j]);
  sm[t] = s;
  __syncthreads();
  for (int off = 128; off > 0; off >>= 1) {
    if (t < off) sm[t] += sm[t + off];
    __syncthreads();
  }
  if (t == 0) partials[b] = sm[0];
}

__global__ void k_scan_combine(int* __restrict__ partials, int* __restrict__ rowptr,
                               int nch, int N) {
  __shared__ int sm[128];
  int t = threadIdx.x;
  int v0 = (t < nch) ? partials[t] : 0;
  sm[t] = v0;
  __syncthreads();
  for (int off = 1; off < 128; off <<= 1) {
    int add = (t >= off) ? sm[t - off] : 0;
    __syncthreads();
    sm[t] += add;
    __syncthreads();
  }
  if (t < nch) partials[t] = sm[t] - v0;
  if (t == 0) rowptr[N] = sm[127];
}

__global__ void k_scan_final(const int* __restrict__ cnt, const int* __restrict__ chunkoff,
                             int* __restrict__ rowptr, int N) {
  __shared__ int sm[256];
  int b = blockIdx.x, t = threadIdx.x;
  int base = b * 1024 + t * 4;
  int v[4]; int s = 0;
  #pragma unroll
  for (int j = 0; j < 4; ++j) { v[j] = (base + j < N) ? pad4(cnt[base + j]) : 0; s += v[j]; }
  sm[t] = s;
  __syncthreads();
  for (int off = 1; off < 256; off <<= 1) {
    int add = (t >= off) ? sm[t - off] : 0;
    __syncthreads();
    sm[t] += add;
    __syncthreads();
  }
  int excl = sm[t] - s;
  int run = chunkoff[b] + excl;
  #pragma unroll
  for (int j = 0; j < 4; ++j) {
    if (base + j < N) rowptr[base + j] = run;
    run += v[j];
  }
}

__global__ void k_dinv(const int* __restrict__ cnt, float* __restrict__ dinv, int N) {
  int n = blockIdx.x * 256 + threadIdx.x;
  if (n < N) dinv[n] = rsqrtf((float)(cnt[n] + 1));
}

__global__ void k_fill(int* __restrict__ p, int val, int total) {
  int i = (blockIdx.x * 256 + threadIdx.x) * 4;
  if (i + 4 <= total) {
    *(int4*)&p[i] = make_int4(val, val, val, val);
  } else {
    for (; i < total; ++i) p[i] = val;
  }
}

// scatter: srcs[rowptr[d] + groupbase2[d,g] + pos[e]] = src[e]
__global__ __launch_bounds__(256)
void k_scatter(const int* __restrict__ src, const int* __restrict__ dst,
               const int* __restrict__ pos, const int* __restrict__ rowptr,
               const int* __restrict__ base2, int* __restrict__ srcs, int E, int NG) {
  int e0 = (blockIdx.x * 256 + threadIdx.x) * 8;
  if (e0 + 8 <= E) {
    int s[8], d[8], p[8];
    *(int4*)&s[0] = *(const int4*)&src[e0];
    *(int4*)&s[4] = *(const int4*)&src[e0 + 4];
    *(int4*)&d[0] = *(const int4*)&dst[e0];
    *(int4*)&d[4] = *(const int4*)&dst[e0 + 4];
    *(int4*)&p[0] = *(const int4*)&pos[e0];
    *(int4*)&p[4] = *(const int4*)&pos[e0 + 4];
    int rp[8], gb[8];
    #pragma unroll
    for (int j = 0; j < 8; ++j) rp[j] = rowptr[d[j]];
    #pragma unroll
    for (int j = 0; j < 8; ++j) gb[j] = base2[d[j] * NG + (s[j] >> GSH)];
    #pragma unroll
    for (int j = 0; j < 8; ++j) srcs[rp[j] + gb[j] + p[j]] = s[j];
  } else {
    for (int e = e0; e < E; ++e) {
      int ss = src[e], dd = dst[e];
      srcs[rowptr[dd] + base2[dd * NG + (ss >> GSH)] + pos[e]] = ss;
    }
  }
}

// ---------------- weight convert/transpose ----------------
__global__ void k_convW(const float* __restrict__ W, ushort* __restrict__ WT, int K) {
  int i = blockIdx.x * 256 + threadIdx.x;
  if (i >= K * HID) return;
  int k = i >> 7, c = i & 127;
  WT[c * K + k] = f2bf(W[i]);
}

// ---------------- GEMM1: x[N,768] f32 @ WT[128,768] -> G = dinv * (x@W1), bf16 ----------------
__global__ __launch_bounds__(256)
void k_gemm1(const float* __restrict__ A, const ushort* __restrict__ WT,
             const float* __restrict__ dinv, ushort* __restrict__ G, const int N) {
  __shared__ ushort lB[2][128 * 64];
  const int tid = threadIdx.x;
  const int lane = tid & 63;
  const int wid = tid >> 6;
  const int lr = lane & 15, lq = lane >> 4;   // lq 0..3
  const int r0 = blockIdx.x * 64 + wid * 16;  // wave owns 16 rows
  int arow = r0 + lr; if (arow > N - 1) arow = N - 1;
  const float* Ap = A + (size_t)arow * IN_DIM + lq * 8;

  auto stageB = [&](int buf, int k0) {
    #pragma unroll
    for (int j = 0; j < 4; ++j) {
      int i = j * 256 + tid;
      int r = i >> 3;
      int c = ((i & 7) ^ (r & 7)) * 8;
      __builtin_amdgcn_global_load_lds((const uint*)(WT + (size_t)r * IN_DIM + k0 + c),
                                       (uint*)&lB[buf][i * 8], 16, 0, 0);
    }
  };

  float4 fa[4];
  auto loadA = [&](int k0) {
    const float* p = Ap + k0;
    fa[0] = *(const float4*)p;
    fa[1] = *(const float4*)(p + 4);
    fa[2] = *(const float4*)(p + 32);
    fa[3] = *(const float4*)(p + 36);
  };

  f32x4 acc[8];
  #pragma unroll
  for (int n = 0; n < 8; ++n) acc[n] = (f32x4){0.f, 0.f, 0.f, 0.f};

  loadA(0);
  stageB(0, 0);
  __syncthreads();

  constexpr int NT = IN_DIM / 64;
  for (int t = 0; t < NT; ++t) {
    const int cur = t & 1;
    bf16x8 av[2];
    {
      uint* u = (uint*)&av[0];
      u[0] = cvtpk(fa[0].x, fa[0].y); u[1] = cvtpk(fa[0].z, fa[0].w);
      u[2] = cvtpk(fa[1].x, fa[1].y); u[3] = cvtpk(fa[1].z, fa[1].w);
      u[4] = cvtpk(fa[2].x, fa[2].y); u[5] = cvtpk(fa[2].z, fa[2].w);
      u[6] = cvtpk(fa[3].x, fa[3].y); u[7] = cvtpk(fa[3].z, fa[3].w);
    }
    if (t + 1 < NT) { loadA((t + 1) * 64); stageB(cur ^ 1, (t + 1) * 64); }
    #pragma unroll
    for (int kk = 0; kk < 2; ++kk) {
      #pragma unroll
      for (int n = 0; n < 8; ++n) {
        int C = n * 16 + lr;
        int slot = (kk * 4 + lq) ^ (C & 7);
        bf16x8 bv = *(const bf16x8*)&lB[cur][C * 64 + slot * 8];
        acc[n] = __builtin_amdgcn_mfma_f32_16x16x32_bf16(av[kk], bv, acc[n], 0, 0, 0);
      }
    }
    __syncthreads();
  }

  float dv[4];
  #pragma unroll
  for (int i = 0; i < 4; ++i) {
    int row = r0 + lq * 4 + i;
    dv[i] = (row < N) ? dinv[row] : 0.f;
  }
  #pragma unroll
  for (int n = 0; n < 8; ++n) {
    #pragma unroll
    for (int i = 0; i < 4; ++i) {
      int row = r0 + lq * 4 + i;
      if (row < N) G[(size_t)row * HID + n * 16 + lr] = f2bf(dv[i] * acc[n][i]);
    }
  }
}

// ---------------- GEMM2: H1[N,128] bf16 @ WT[128,128] -> G = dinv*(H1@W2), bf16 ----------------
__global__ __launch_bounds__(256)
void k_gemm2(const ushort* __restrict__ A, const ushort* __restrict__ WT,
             const float* __restrict__ dinv, ushort* __restrict__ G, const int N) {
  __shared__ ushort lA[2][128 * 64];
  __shared__ ushort lB[2][128 * 64];
  const int tid = threadIdx.x;
  const int lane = tid & 63;
  const int wid = tid >> 6;
  const int wm = wid >> 1, wn = wid & 1;
  const int row0 = blockIdx.x * 128;
  const int lr = lane & 15;
  const int lk8 = lane >> 4;
  constexpr int K = HID;

  auto stage = [&](int buf, int k0) {
    #pragma unroll
    for (int j = 0; j < 4; ++j) {
      int i = j * 256 + tid;
      int r = i >> 3;
      int c = ((i & 7) ^ (r & 7)) * 8;
      int ga = row0 + r; ga = ga < N ? ga : N - 1;
      __builtin_amdgcn_global_load_lds((const uint*)(A + (size_t)ga * K + k0 + c),
                                       (uint*)&lA[buf][i * 8], 16, 0, 0);
      __builtin_amdgcn_global_load_lds((const uint*)(WT + (size_t)r * K + k0 + c),
                                       (uint*)&lB[buf][i * 8], 16, 0, 0);
    }
  };

  f32x4 acc[4][4];
  #pragma unroll
  for (int m = 0; m < 4; ++m)
    #pragma unroll
    for (int n = 0; n < 4; ++n)
      acc[m][n] = (f32x4){0.f, 0.f, 0.f, 0.f};

  constexpr int NT = K / 64;
  stage(0, 0);
  __syncthreads();

  for (int t = 0; t < NT; ++t) {
    const int cur = t & 1;
    if (t + 1 < NT) stage(cur ^ 1, (t + 1) * 64);
    #pragma unroll
    for (int kk = 0; kk < 2; ++kk) {
      bf16x8 av[4], bv[4];
      #pragma unroll
      for (int m = 0; m < 4; ++m) {
        int R = wm * 64 + m * 16 + lr;
        int slot = (kk * 4 + lk8) ^ (R & 7);
        av[m] = *(const bf16x8*)&lA[cur][R * 64 + slot * 8];
      }
      #pragma unroll
      for (int n = 0; n < 4; ++n) {
        int C = wn * 64 + n * 16 + lr;
        int slot = (kk * 4 + lk8) ^ (C & 7);
        bv[n] = *(const bf16x8*)&lB[cur][C * 64 + slot * 8];
      }
      #pragma unroll
      for (int m = 0; m < 4; ++m)
        #pragma unroll
        for (int n = 0; n < 4; ++n)
          acc[m][n] = __builtin_amdgcn_mfma_f32_16x16x32_bf16(av[m], bv[n], acc[m][n], 0, 0, 0);
    }
    __syncthreads();
  }

  #pragma unroll
  for (int m = 0; m < 4; ++m) {
    #pragma unroll
    for (int i = 0; i < 4; ++i) {
      int row = row0 + wm * 64 + m * 16 + (lane >> 4) * 4 + i;
      if (row < N) {
        float dv = dinv[row];
        #pragma unroll
        for (int n = 0; n < 4; ++n) {
          int col = wn * 64 + n * 16 + lr;
          G[(size_t)row * HID + col] = f2bf(dv * acc[m][n][i]);
        }
      }
    }
  }
}

// ---------------- aggregation: full-row gathers, 32-deep pipeline ----------------
// G rows pre-scaled by dinv[src]; pad src = N with G[N] = 0.
// One wave per node; lane holds dims (2*lane, 2*lane+1) as packed bf16 uint.

#define GL(v, s) uint v = Gp[(size_t)(s) * 64 + lane];
#define AC(v) { a0 += lof(v); a1 += hif(v); }

__device__ __forceinline__ void agg32(const uint* __restrict__ Gp,
                                      const int* __restrict__ srcs,
                                      int i, int lane, float& a0, float& a1) {
  int4 sa = *(const int4*)&srcs[i];
  int4 sb = *(const int4*)&srcs[i + 4];
  int4 sc = *(const int4*)&srcs[i + 8];
  int4 sd = *(const int4*)&srcs[i + 12];
  int4 se = *(const int4*)&srcs[i + 16];
  int4 sf = *(const int4*)&srcs[i + 20];
  int4 sg = *(const int4*)&srcs[i + 24];
  int4 sh = *(const int4*)&srcs[i + 28];
  GL(h00, sa.x) GL(h01, sa.y) GL(h02, sa.z) GL(h03, sa.w)
  GL(h04, sb.x) GL(h05, sb.y) GL(h06, sb.z) GL(h07, sb.w)
  GL(h08, sc.x) GL(h09, sc.y) GL(h10, sc.z) GL(h11, sc.w)
  GL(h12, sd.x) GL(h13, sd.y) GL(h14, sd.z) GL(h15, sd.w)
  GL(h16, se.x) GL(h17, se.y) GL(h18, se.z) GL(h19, se.w)
  GL(h20, sf.x) GL(h21, sf.y) GL(h22, sf.z) GL(h23, sf.w)
  GL(h24, sg.x) GL(h25, sg.y) GL(h26, sg.z) GL(h27, sg.w)
  GL(h28, sh.x) GL(h29, sh.y) GL(h30, sh.z) GL(h31, sh.w)
  __builtin_amdgcn_sched_barrier(0);   // all 32 gathers issued before consumption
  AC(h00) AC(h01) AC(h02) AC(h03) AC(h04) AC(h05) AC(h06) AC(h07)
  AC(h08) AC(h09) AC(h10) AC(h11) AC(h12) AC(h13) AC(h14) AC(h15)
  AC(h16) AC(h17) AC(h18) AC(h19) AC(h20) AC(h21) AC(h22) AC(h23)
  AC(h24) AC(h25) AC(h26) AC(h27) AC(h28) AC(h29) AC(h30) AC(h31)
}

__device__ __forceinline__ void agg16(const uint* __restrict__ Gp,
                                      const int* __restrict__ srcs,
                                      int i, int lane, float& a0, float& a1) {
  int4 sa = *(const int4*)&srcs[i];
  int4 sb = *(const int4*)&srcs[i + 4];
  int4 sc = *(const int4*)&srcs[i + 8];
  int4 sd = *(const int4*)&srcs[i + 12];
  GL(h00, sa.x) GL(h01, sa.y) GL(h02, sa.z) GL(h03, sa.w)
  GL(h04, sb.x) GL(h05, sb.y) GL(h06, sb.z) GL(h07, sb.w)
  GL(h08, sc.x) GL(h09, sc.y) GL(h10, sc.z) GL(h11, sc.w)
  GL(h12, sd.x) GL(h13, sd.y) GL(h14, sd.z) GL(h15, sd.w)
  __builtin_amdgcn_sched_barrier(0);
  AC(h00) AC(h01) AC(h02) AC(h03) AC(h04) AC(h05) AC(h06) AC(h07)
  AC(h08) AC(h09) AC(h10) AC(h11) AC(h12) AC(h13) AC(h14) AC(h15)
}

__device__ __forceinline__ void agg4(const uint* __restrict__ Gp,
                                     const int* __restrict__ srcs,
                                     int i, int lane, float& a0, float& a1) {
  int4 sa = *(const int4*)&srcs[i];
  GL(h00, sa.x) GL(h01, sa.y) GL(h02, sa.z) GL(h03, sa.w)
  __builtin_amdgcn_sched_barrier(0);
  AC(h00) AC(h01) AC(h02) AC(h03)
}

__global__ __launch_bounds__(256)
void k_agg(const uint* __restrict__ Gp, const int* __restrict__ srcs,
           const int* __restrict__ rowptr, const float* __restrict__ dinv,
           const float* __restrict__ bias, uint* __restrict__ Ou, int N) {
  int w = (blockIdx.x * 256 + threadIdx.x) >> 6;
  if (w >= N) return;
  int lane = threadIdx.x & 63;
  int start = rowptr[w], end = rowptr[w + 1];
  float di = dinv[w];
  uint hv = Gp[(size_t)w * 64 + lane];   // self (pre-scaled by dinv[w])
  float a0 = lof(hv), a1 = hif(hv);
  int i = start;
  for (; i + 32 <= end; i += 32) agg32(Gp, srcs, i, lane, a0, a1);
  for (; i + 16 <= end; i += 16) agg16(Gp, srcs, i, lane, a0, a1);
  for (; i < end; i += 4)        agg4(Gp, srcs, i, lane, a0, a1);
  float2 bb = ((const float2*)bias)[lane];
  a0 = fmaxf(fmaf(di, a0, bb.x), 0.f);
  a1 = fmaxf(fmaf(di, a1, bb.y), 0.f);
  Ou[(size_t)w * 64 + lane] = (uint)f2bf(a0) | ((uint)f2bf(a1) << 16);
}

// layer-2 aggregation with fused classifier: logits = relu(...) @ Wc + bc
__global__ __launch_bounds__(256)
void k_agg_final(const uint* __restrict__ Gp, const int* __restrict__ srcs,
                 const int* __restrict__ rowptr, const float* __restrict__ dinv,
                 const float* __restrict__ bias, const float* __restrict__ Wc,
                 const float* __restrict__ bc, float* __restrict__ out, int N) {
  int w = (blockIdx.x * 256 + threadIdx.x) >> 6;
  if (w >= N) return;
  int lane = threadIdx.x & 63;
  int start = rowptr[w], end = rowptr[w + 1];
  float di = dinv[w];
  uint hv = Gp[(size_t)w * 64 + lane];
  float a0 = lof(hv), a1 = hif(hv);
  int i = start;
  for (; i + 32 <= end; i += 32) agg32(Gp, srcs, i, lane, a0, a1);
  for (; i + 16 <= end; i += 16) agg16(Gp, srcs, i, lane, a0, a1);
  for (; i < end; i += 4)        agg4(Gp, srcs, i, lane, a0, a1);
  float2 bb = ((const float2*)bias)[lane];
  a0 = fmaxf(fmaf(di, a0, bb.x), 0.f);
  a1 = fmaxf(fmaf(di, a1, bb.y), 0.f);
  // classifier: lane owns dims 2*lane, 2*lane+1
  const float* w0 = &Wc[(2 * lane) * NC];
  #pragma unroll
  for (int c = 0; c < NC; ++c) {
    float s = a0 * w0[c] + a1 * w0[NC + c];
    #pragma unroll
    for (int off = 32; off > 0; off >>= 1) s += __shfl_xor(s, off, 64);
    if (lane == 0) out[(size_t)w * NC + c] = s + bc[c];
  }
}

extern "C" void kernel_launch(void* const* d_in, const int* in_sizes, int n_in,
                              void* d_out, int out_size, void* d_ws, size_t ws_size,
                              hipStream_t stream) {
  const float* x  = (const float*)d_in[0];
  const int*   ei = (const int*)d_in[1];
  const float* W1 = (const float*)d_in[2];
  const float* b1 = (const float*)d_in[3];
  const float* W2 = (const float*)d_in[4];
  const float* b2 = (const float*)d_in[5];
  const float* Wc = (const float*)d_in[6];
  const float* bc = (const float*)d_in[7];
  float* out = (float*)d_out;

  const int N = in_sizes[0] / IN_DIM;
  const int E = in_sizes[1] / 2;
  const int* src = ei;
  const int* dst = ei + E;
  const int NG = ((N - 1) >> GSH) + 1;     // src-groups of 8192 nodes
  const int CSRCAP = E + 3 * N + 64;

  char* ws = (char*)d_ws;
  size_t off = 0;
  auto alloc = [&](size_t bytes) -> void* {
    off = (off + 255) & ~(size_t)255;
    void* p = ws + off;
    off += bytes;
    return p;
  };
  ushort* H0     = (ushort*)alloc((size_t)(N + 1) * HID * 2);  // G buffers (row N = pad = 0)
  ushort* H1     = (ushort*)alloc((size_t)(N + 1) * HID * 2);
  int*    srcs   = (int*)alloc((size_t)CSRCAP * 4);
  int*    cnt2   = (int*)alloc((size_t)N * NG * 4);  // (dst,group) counts -> group bases
  int*    cnt    = (int*)alloc((size_t)N * 4);
  int*    pos    = (int*)alloc((size_t)E * 4);
  int*    rowptr = (int*)alloc((size_t)(N + 1) * 4);
  float*  dinv   = (float*)alloc((size_t)N * 4);
  int*    partials = (int*)alloc(512);
  ushort* W1T    = (ushort*)alloc((size_t)IN_DIM * HID * 2);
  ushort* W2T    = (ushort*)alloc((size_t)HID * HID * 2);

  hipMemsetAsync(cnt2, 0, (size_t)N * NG * 4, stream);
  hipMemsetAsync(H0 + (size_t)N * HID, 0, HID * 2, stream);   // pad row G[N] = 0

  k_convW<<<(IN_DIM * HID + 255) / 256, 256, 0, stream>>>(W1, W1T, IN_DIM);
  k_convW<<<(HID * HID + 255) / 256, 256, 0, stream>>>(W2, W2T, HID);

  k_count<<<(E + 1023) / 1024, 256, 0, stream>>>(src, dst, cnt2, pos, E, NG);
  k_rowscan<<<(N + 255) / 256, 256, 0, stream>>>(cnt2, cnt, N, NG);
  int nch = (N + 1023) >> 10;
  k_scan_partial<<<nch, 256, 0, stream>>>(cnt, partials, N);
  k_scan_combine<<<1, 128, 0, stream>>>(partials, rowptr, nch, N);
  k_scan_final<<<nch, 256, 0, stream>>>(cnt, partials, rowptr, N);
  k_dinv<<<(N + 255) / 256, 256, 0, stream>>>(cnt, dinv, N);
  k_fill<<<(CSRCAP + 1023) / 1024, 256, 0, stream>>>(srcs, N, CSRCAP);
  k_scatter<<<(E + 2047) / 2048, 256, 0, stream>>>(src, dst, pos, rowptr, cnt2, srcs, E, NG);

  k_gemm1<<<(N + 63) / 64, 256, 0, stream>>>(x, W1T, dinv, H0, N);
  k_agg<<<(N + 3) / 4, 256, 0, stream>>>((const uint*)H0, srcs, rowptr, dinv, b1,
                                         (uint*)H1, N);
  k_gemm2<<<(N + 127) / 128, 256, 0, stream>>>(H1, W2T, dinv, H0, N);
  k_agg_final<<<(N + 3) / 4, 256, 0, stream>>>((const uint*)H0, srcs, rowptr, dinv, b2,
                                               Wc, bc, out, N);
}

// Round 9
// 587.269 us; speedup vs baseline: 1.0363x; 1.0363x over previous
//
#include <hip/hip_runtime.h>
#include <hip/hip_bf16.h>

#define IN_DIM 768
#define HID 128
#define NC 7

typedef __attribute__((ext_vector_type(8))) short bf16x8;
typedef __attribute__((ext_vector_type(4))) float f32x4;

__device__ __forceinline__ ushort f2bf(float f) {
  uint u = __float_as_uint(f);
  u += 0x7fffu + ((u >> 16) & 1u);   // round-to-nearest-even
  return (ushort)(u >> 16);
}
__device__ __forceinline__ float lof(uint v) { return __uint_as_float(v << 16); }
__device__ __forceinline__ float hif(uint v) { return __uint_as_float(v & 0xffff0000u); }
__device__ __forceinline__ uint cvtpk(float lo, float hi) {
  uint r;
  asm("v_cvt_pk_bf16_f32 %0, %1, %2" : "=v"(r) : "v"(lo), "v"(hi));
  return r;
}

// ---------------- CSR build (r6-proven) ----------------

__global__ __launch_bounds__(256) void k_count(const int* __restrict__ dst,
                                               int* __restrict__ cnt,
                                               int* __restrict__ pos, int E) {
  int e0 = (blockIdx.x * 256 + threadIdx.x) * 4;
  if (e0 + 4 <= E) {
    int4 d = *(const int4*)&dst[e0];
    int4 p;
    p.x = atomicAdd(&cnt[d.x], 1);
    p.y = atomicAdd(&cnt[d.y], 1);
    p.z = atomicAdd(&cnt[d.z], 1);
    p.w = atomicAdd(&cnt[d.w], 1);
    *(int4*)&pos[e0] = p;
  } else {
    for (int e = e0; e < E; ++e) pos[e] = atomicAdd(&cnt[dst[e]], 1);
  }
}

__device__ __forceinline__ int pad4(int c) { return (c + 3) & ~3; }

__global__ void k_scan_partial(const int* __restrict__ cnt, int* __restrict__ partials, int N) {
  __shared__ int sm[256];
  int b = blockIdx.x, t = threadIdx.x;
  int base = b * 1024 + t * 4;
  int s = 0;
  #pragma unroll
  for (int j = 0; j < 4; ++j) if (base + j < N) s += pad4(cnt[base + j]);
  sm[t] = s;
  __syncthreads();
  for (int off = 128; off > 0; off >>= 1) {
    if (t < off) sm[t] += sm[t + off];
    __syncthreads();
  }
  if (t == 0) partials[b] = sm[0];
}

__global__ void k_scan_combine(int* __restrict__ partials, int* __restrict__ rowptr,
                               int nch, int N) {
  __shared__ int sm[128];
  int t = threadIdx.x;
  int v0 = (t < nch) ? partials[t] : 0;
  sm[t] = v0;
  __syncthreads();
  for (int off = 1; off < 128; off <<= 1) {
    int add = (t >= off) ? sm[t - off] : 0;
    __syncthreads();
    sm[t] += add;
    __syncthreads();
  }
  if (t < nch) partials[t] = sm[t] - v0;
  if (t == 0) rowptr[N] = sm[127];
}

__global__ void k_scan_final(const int* __restrict__ cnt, const int* __restrict__ chunkoff,
                             int* __restrict__ rowptr, int N) {
  __shared__ int sm[256];
  int b = blockIdx.x, t = threadIdx.x;
  int base = b * 1024 + t * 4;
  int v[4]; int s = 0;
  #pragma unroll
  for (int j = 0; j < 4; ++j) { v[j] = (base + j < N) ? pad4(cnt[base + j]) : 0; s += v[j]; }
  sm[t] = s;
  __syncthreads();
  for (int off = 1; off < 256; off <<= 1) {
    int add = (t >= off) ? sm[t - off] : 0;
    __syncthreads();
    sm[t] += add;
    __syncthreads();
  }
  int excl = sm[t] - s;
  int run = chunkoff[b] + excl;
  #pragma unroll
  for (int j = 0; j < 4; ++j) {
    if (base + j < N) rowptr[base + j] = run;
    run += v[j];
  }
}

__global__ void k_dinv(const int* __restrict__ cnt, float* __restrict__ dinv, int N) {
  int n = blockIdx.x * 256 + threadIdx.x;
  if (n < N) dinv[n] = rsqrtf((float)(cnt[n] + 1));
}

__global__ void k_fill(int* __restrict__ p, int val, int total) {
  int i = (blockIdx.x * 256 + threadIdx.x) * 4;
  if (i + 4 <= total) {
    *(int4*)&p[i] = make_int4(val, val, val, val);
  } else {
    for (; i < total; ++i) p[i] = val;
  }
}

__global__ __launch_bounds__(256)
void k_scatter(const int* __restrict__ src, const int* __restrict__ dst,
               const int* __restrict__ pos, const int* __restrict__ rowptr,
               int* __restrict__ srcs, int E) {
  int e0 = (blockIdx.x * 256 + threadIdx.x) * 8;
  if (e0 + 8 <= E) {
    int s[8], d[8], p[8];
    *(int4*)&s[0] = *(const int4*)&src[e0];
    *(int4*)&s[4] = *(const int4*)&src[e0 + 4];
    *(int4*)&d[0] = *(const int4*)&dst[e0];
    *(int4*)&d[4] = *(const int4*)&dst[e0 + 4];
    *(int4*)&p[0] = *(const int4*)&pos[e0];
    *(int4*)&p[4] = *(const int4*)&pos[e0 + 4];
    int rp[8];
    #pragma unroll
    for (int j = 0; j < 8; ++j) rp[j] = rowptr[d[j]];
    #pragma unroll
    for (int j = 0; j < 8; ++j) srcs[rp[j] + p[j]] = s[j];
  } else {
    for (int e = e0; e < E; ++e) srcs[rowptr[dst[e]] + pos[e]] = src[e];
  }
}

// ---------------- weight convert/transpose (r6-proven) ----------------
__global__ void k_convW(const float* __restrict__ W, ushort* __restrict__ WT, int K) {
  int i = blockIdx.x * 256 + threadIdx.x;
  if (i >= K * HID) return;
  int k = i >> 7, c = i & 127;
  WT[c * K + k] = f2bf(W[i]);
}

// ---------------- GEMM1: x[N,768] f32 @ WT[128,768] -> G = dinv*(x@W1), bf16 ----------------
// 256 threads / 4 waves (r6-proven staging), but 128 rows per block: two 64-row
// halves share one staged B tile; each bv LDS read feeds two MFMAs.
__global__ __launch_bounds__(256)
void k_gemm1(const float* __restrict__ A, const ushort* __restrict__ WT,
             const float* __restrict__ dinv, ushort* __restrict__ G, const int N) {
  __shared__ ushort lB[2][128 * 64];
  const int tid = threadIdx.x;
  const int lane = tid & 63;
  const int wid = tid >> 6;                    // 0..3
  const int lr = lane & 15, lq = lane >> 4;    // lq 0..3
  const int rb = blockIdx.x * 128 + wid * 16;  // half-0 row base for this wave
  int ar0 = rb + lr;      if (ar0 > N - 1) ar0 = N - 1;
  int ar1 = rb + 64 + lr; if (ar1 > N - 1) ar1 = N - 1;
  const float* Ap0 = A + (size_t)ar0 * IN_DIM + lq * 8;
  const float* Ap1 = A + (size_t)ar1 * IN_DIM + lq * 8;

  auto stageB = [&](int buf, int k0) {
    #pragma unroll
    for (int j = 0; j < 4; ++j) {
      int i = j * 256 + tid;
      int r = i >> 3;
      int c = ((i & 7) ^ (r & 7)) * 8;
      __builtin_amdgcn_global_load_lds((const uint*)(WT + (size_t)r * IN_DIM + k0 + c),
                                       (uint*)&lB[buf][i * 8], 16, 0, 0);
    }
  };

  float4 fa0[4], fa1[4];
  auto loadA = [&](int k0) {
    const float* p0 = Ap0 + k0;
    fa0[0] = *(const float4*)p0;
    fa0[1] = *(const float4*)(p0 + 4);
    fa0[2] = *(const float4*)(p0 + 32);
    fa0[3] = *(const float4*)(p0 + 36);
    const float* p1 = Ap1 + k0;
    fa1[0] = *(const float4*)p1;
    fa1[1] = *(const float4*)(p1 + 4);
    fa1[2] = *(const float4*)(p1 + 32);
    fa1[3] = *(const float4*)(p1 + 36);
  };

  f32x4 acc0[8], acc1[8];
  #pragma unroll
  for (int n = 0; n < 8; ++n) {
    acc0[n] = (f32x4){0.f, 0.f, 0.f, 0.f};
    acc1[n] = (f32x4){0.f, 0.f, 0.f, 0.f};
  }

  loadA(0);
  stageB(0, 0);
  __syncthreads();

  constexpr int NT = IN_DIM / 64;
  for (int t = 0; t < NT; ++t) {
    const int cur = t & 1;
    bf16x8 av0[2], av1[2];
    {
      uint* u = (uint*)&av0[0];
      u[0] = cvtpk(fa0[0].x, fa0[0].y); u[1] = cvtpk(fa0[0].z, fa0[0].w);
      u[2] = cvtpk(fa0[1].x, fa0[1].y); u[3] = cvtpk(fa0[1].z, fa0[1].w);
      u[4] = cvtpk(fa0[2].x, fa0[2].y); u[5] = cvtpk(fa0[2].z, fa0[2].w);
      u[6] = cvtpk(fa0[3].x, fa0[3].y); u[7] = cvtpk(fa0[3].z, fa0[3].w);
      uint* v = (uint*)&av1[0];
      v[0] = cvtpk(fa1[0].x, fa1[0].y); v[1] = cvtpk(fa1[0].z, fa1[0].w);
      v[2] = cvtpk(fa1[1].x, fa1[1].y); v[3] = cvtpk(fa1[1].z, fa1[1].w);
      v[4] = cvtpk(fa1[2].x, fa1[2].y); v[5] = cvtpk(fa1[2].z, fa1[2].w);
      v[6] = cvtpk(fa1[3].x, fa1[3].y); v[7] = cvtpk(fa1[3].z, fa1[3].w);
    }
    if (t + 1 < NT) { loadA((t + 1) * 64); stageB(cur ^ 1, (t + 1) * 64); }
    #pragma unroll
    for (int kk = 0; kk < 2; ++kk) {
      #pragma unroll
      for (int n = 0; n < 8; ++n) {
        int C = n * 16 + lr;
        int slot = (kk * 4 + lq) ^ (C & 7);
        bf16x8 bv = *(const bf16x8*)&lB[cur][C * 64 + slot * 8];
        acc0[n] = __builtin_amdgcn_mfma_f32_16x16x32_bf16(av0[kk], bv, acc0[n], 0, 0, 0);
        acc1[n] = __builtin_amdgcn_mfma_f32_16x16x32_bf16(av1[kk], bv, acc1[n], 0, 0, 0);
      }
    }
    __syncthreads();
  }

  #pragma unroll
  for (int i = 0; i < 4; ++i) {
    int row0 = rb + lq * 4 + i;
    int row1 = rb + 64 + lq * 4 + i;
    float dv0 = (row0 < N) ? dinv[row0] : 0.f;
    float dv1 = (row1 < N) ? dinv[row1] : 0.f;
    #pragma unroll
    for (int n = 0; n < 8; ++n) {
      if (row0 < N) G[(size_t)row0 * HID + n * 16 + lr] = f2bf(dv0 * acc0[n][i]);
      if (row1 < N) G[(size_t)row1 * HID + n * 16 + lr] = f2bf(dv1 * acc1[n][i]);
    }
  }
}

// ---------------- GEMM2: H1[N,128] bf16 @ WT[128,128] -> G = dinv*(H1@W2), bf16 ----------------
__global__ __launch_bounds__(256)
void k_gemm2(const ushort* __restrict__ A, const ushort* __restrict__ WT,
             const float* __restrict__ dinv, ushort* __restrict__ G, const int N) {
  __shared__ ushort lA[2][128 * 64];
  __shared__ ushort lB[2][128 * 64];
  const int tid = threadIdx.x;
  const int lane = tid & 63;
  const int wid = tid >> 6;
  const int wm = wid >> 1, wn = wid & 1;
  const int row0 = blockIdx.x * 128;
  const int lr = lane & 15;
  const int lk8 = lane >> 4;
  constexpr int K = HID;

  auto stage = [&](int buf, int k0) {
    #pragma unroll
    for (int j = 0; j < 4; ++j) {
      int i = j * 256 + tid;
      int r = i >> 3;
      int c = ((i & 7) ^ (r & 7)) * 8;
      int ga = row0 + r; ga = ga < N ? ga : N - 1;
      __builtin_amdgcn_global_load_lds((const uint*)(A + (size_t)ga * K + k0 + c),
                                       (uint*)&lA[buf][i * 8], 16, 0, 0);
      __builtin_amdgcn_global_load_lds((const uint*)(WT + (size_t)r * K + k0 + c),
                                       (uint*)&lB[buf][i * 8], 16, 0, 0);
    }
  };

  f32x4 acc[4][4];
  #pragma unroll
  for (int m = 0; m < 4; ++m)
    #pragma unroll
    for (int n = 0; n < 4; ++n)
      acc[m][n] = (f32x4){0.f, 0.f, 0.f, 0.f};

  constexpr int NT = K / 64;
  stage(0, 0);
  __syncthreads();

  for (int t = 0; t < NT; ++t) {
    const int cur = t & 1;
    if (t + 1 < NT) stage(cur ^ 1, (t + 1) * 64);
    #pragma unroll
    for (int kk = 0; kk < 2; ++kk) {
      bf16x8 av[4], bv[4];
      #pragma unroll
      for (int m = 0; m < 4; ++m) {
        int R = wm * 64 + m * 16 + lr;
        int slot = (kk * 4 + lk8) ^ (R & 7);
        av[m] = *(const bf16x8*)&lA[cur][R * 64 + slot * 8];
      }
      #pragma unroll
      for (int n = 0; n < 4; ++n) {
        int C = wn * 64 + n * 16 + lr;
        int slot = (kk * 4 + lk8) ^ (C & 7);
        bv[n] = *(const bf16x8*)&lB[cur][C * 64 + slot * 8];
      }
      #pragma unroll
      for (int m = 0; m < 4; ++m)
        #pragma unroll
        for (int n = 0; n < 4; ++n)
          acc[m][n] = __builtin_amdgcn_mfma_f32_16x16x32_bf16(av[m], bv[n], acc[m][n], 0, 0, 0);
    }
    __syncthreads();
  }

  #pragma unroll
  for (int m = 0; m < 4; ++m) {
    #pragma unroll
    for (int i = 0; i < 4; ++i) {
      int row = row0 + wm * 64 + m * 16 + (lane >> 4) * 4 + i;
      if (row < N) {
        float dv = dinv[row];
        #pragma unroll
        for (int n = 0; n < 4; ++n) {
          int col = wn * 64 + n * 16 + lr;
          G[(size_t)row * HID + col] = f2bf(dv * acc[m][n][i]);
        }
      }
    }
  }
}

// ---------------- aggregation: full-row gathers, 32-deep pipeline (r6-proven) ----------------
// G rows pre-scaled by dinv[src]; pad src = N with G[N] = 0.

#define GL(v, s) uint v = Gp[(size_t)(s) * 64 + lane];
#define AC(v) { a0 += lof(v); a1 += hif(v); }

__device__ __forceinline__ void agg32(const uint* __restrict__ Gp,
                                      const int* __restrict__ srcs,
                                      int i, int lane, float& a0, float& a1) {
  int4 sa = *(const int4*)&srcs[i];
  int4 sb = *(const int4*)&srcs[i + 4];
  int4 sc = *(const int4*)&srcs[i + 8];
  int4 sd = *(const int4*)&srcs[i + 12];
  int4 se = *(const int4*)&srcs[i + 16];
  int4 sf = *(const int4*)&srcs[i + 20];
  int4 sg = *(const int4*)&srcs[i + 24];
  int4 sh = *(const int4*)&srcs[i + 28];
  GL(h00, sa.x) GL(h01, sa.y) GL(h02, sa.z) GL(h03, sa.w)
  GL(h04, sb.x) GL(h05, sb.y) GL(h06, sb.z) GL(h07, sb.w)
  GL(h08, sc.x) GL(h09, sc.y) GL(h10, sc.z) GL(h11, sc.w)
  GL(h12, sd.x) GL(h13, sd.y) GL(h14, sd.z) GL(h15, sd.w)
  GL(h16, se.x) GL(h17, se.y) GL(h18, se.z) GL(h19, se.w)
  GL(h20, sf.x) GL(h21, sf.y) GL(h22, sf.z) GL(h23, sf.w)
  GL(h24, sg.x) GL(h25, sg.y) GL(h26, sg.z) GL(h27, sg.w)
  GL(h28, sh.x) GL(h29, sh.y) GL(h30, sh.z) GL(h31, sh.w)
  __builtin_amdgcn_sched_barrier(0);
  AC(h00) AC(h01) AC(h02) AC(h03) AC(h04) AC(h05) AC(h06) AC(h07)
  AC(h08) AC(h09) AC(h10) AC(h11) AC(h12) AC(h13) AC(h14) AC(h15)
  AC(h16) AC(h17) AC(h18) AC(h19) AC(h20) AC(h21) AC(h22) AC(h23)
  AC(h24) AC(h25) AC(h26) AC(h27) AC(h28) AC(h29) AC(h30) AC(h31)
}

__device__ __forceinline__ void agg16(const uint* __restrict__ Gp,
                                      const int* __restrict__ srcs,
                                      int i, int lane, float& a0, float& a1) {
  int4 sa = *(const int4*)&srcs[i];
  int4 sb = *(const int4*)&srcs[i + 4];
  int4 sc = *(const int4*)&srcs[i + 8];
  int4 sd = *(const int4*)&srcs[i + 12];
  GL(h00, sa.x) GL(h01, sa.y) GL(h02, sa.z) GL(h03, sa.w)
  GL(h04, sb.x) GL(h05, sb.y) GL(h06, sb.z) GL(h07, sb.w)
  GL(h08, sc.x) GL(h09, sc.y) GL(h10, sc.z) GL(h11, sc.w)
  GL(h12, sd.x) GL(h13, sd.y) GL(h14, sd.z) GL(h15, sd.w)
  __builtin_amdgcn_sched_barrier(0);
  AC(h00) AC(h01) AC(h02) AC(h03) AC(h04) AC(h05) AC(h06) AC(h07)
  AC(h08) AC(h09) AC(h10) AC(h11) AC(h12) AC(h13) AC(h14) AC(h15)
}

__device__ __forceinline__ void agg4(const uint* __restrict__ Gp,
                                     const int* __restrict__ srcs,
                                     int i, int lane, float& a0, float& a1) {
  int4 sa = *(const int4*)&srcs[i];
  GL(h00, sa.x) GL(h01, sa.y) GL(h02, sa.z) GL(h03, sa.w)
  __builtin_amdgcn_sched_barrier(0);
  AC(h00) AC(h01) AC(h02) AC(h03)
}

__global__ __launch_bounds__(256)
void k_agg(const uint* __restrict__ Gp, const int* __restrict__ srcs,
           const int* __restrict__ rowptr, const float* __restrict__ dinv,
           const float* __restrict__ bias, uint* __restrict__ Ou, int N) {
  int w = (blockIdx.x * 256 + threadIdx.x) >> 6;
  if (w >= N) return;
  int lane = threadIdx.x & 63;
  int start = rowptr[w], end = rowptr[w + 1];
  float di = dinv[w];
  uint hv = Gp[(size_t)w * 64 + lane];
  float a0 = lof(hv), a1 = hif(hv);
  int i = start;
  for (; i + 32 <= end; i += 32) agg32(Gp, srcs, i, lane, a0, a1);
  for (; i + 16 <= end; i += 16) agg16(Gp, srcs, i, lane, a0, a1);
  for (; i < end; i += 4)        agg4(Gp, srcs, i, lane, a0, a1);
  float2 bb = ((const float2*)bias)[lane];
  a0 = fmaxf(fmaf(di, a0, bb.x), 0.f);
  a1 = fmaxf(fmaf(di, a1, bb.y), 0.f);
  Ou[(size_t)w * 64 + lane] = (uint)f2bf(a0) | ((uint)f2bf(a1) << 16);
}

__global__ __launch_bounds__(256)
void k_agg_final(const uint* __restrict__ Gp, const int* __restrict__ srcs,
                 const int* __restrict__ rowptr, const float* __restrict__ dinv,
                 const float* __restrict__ bias, const float* __restrict__ Wc,
                 const float* __restrict__ bc, float* __restrict__ out, int N) {
  int w = (blockIdx.x * 256 + threadIdx.x) >> 6;
  if (w >= N) return;
  int lane = threadIdx.x & 63;
  int start = rowptr[w], end = rowptr[w + 1];
  float di = dinv[w];
  uint hv = Gp[(size_t)w * 64 + lane];
  float a0 = lof(hv), a1 = hif(hv);
  int i = start;
  for (; i + 32 <= end; i += 32) agg32(Gp, srcs, i, lane, a0, a1);
  for (; i + 16 <= end; i += 16) agg16(Gp, srcs, i, lane, a0, a1);
  for (; i < end; i += 4)        agg4(Gp, srcs, i, lane, a0, a1);
  float2 bb = ((const float2*)bias)[lane];
  a0 = fmaxf(fmaf(di, a0, bb.x), 0.f);
  a1 = fmaxf(fmaf(di, a1, bb.y), 0.f);
  const float* w0 = &Wc[(2 * lane) * NC];
  #pragma unroll
  for (int c = 0; c < NC; ++c) {
    float s = a0 * w0[c] + a1 * w0[NC + c];
    #pragma unroll
    for (int off = 32; off > 0; off >>= 1) s += __shfl_xor(s, off, 64);
    if (lane == 0) out[(size_t)w * NC + c] = s + bc[c];
  }
}

extern "C" void kernel_launch(void* const* d_in, const int* in_sizes, int n_in,
                              void* d_out, int out_size, void* d_ws, size_t ws_size,
                              hipStream_t stream) {
  const float* x  = (const float*)d_in[0];
  const int*   ei = (const int*)d_in[1];
  const float* W1 = (const float*)d_in[2];
  const float* b1 = (const float*)d_in[3];
  const float* W2 = (const float*)d_in[4];
  const float* b2 = (const float*)d_in[5];
  const float* Wc = (const float*)d_in[6];
  const float* bc = (const float*)d_in[7];
  float* out = (float*)d_out;

  const int N = in_sizes[0] / IN_DIM;
  const int E = in_sizes[1] / 2;
  const int* src = ei;
  const int* dst = ei + E;
  const int CSRCAP = E + 3 * N + 64;

  char* ws = (char*)d_ws;
  size_t off = 0;
  auto alloc = [&](size_t bytes) -> void* {
    off = (off + 255) & ~(size_t)255;
    void* p = ws + off;
    off += bytes;
    return p;
  };
  ushort* H0     = (ushort*)alloc((size_t)(N + 1) * HID * 2);  // G buffers (row N = pad = 0)
  ushort* H1     = (ushort*)alloc((size_t)(N + 1) * HID * 2);
  int*    srcs   = (int*)alloc((size_t)CSRCAP * 4);
  int*    cnt    = (int*)alloc((size_t)N * 4);
  int*    pos    = (int*)alloc((size_t)E * 4);
  int*    rowptr = (int*)alloc((size_t)(N + 1) * 4);
  float*  dinv   = (float*)alloc((size_t)N * 4);
  int*    partials = (int*)alloc(512);
  ushort* W1T    = (ushort*)alloc((size_t)IN_DIM * HID * 2);
  ushort* W2T    = (ushort*)alloc((size_t)HID * HID * 2);

  hipMemsetAsync(cnt, 0, (size_t)N * 4, stream);
  hipMemsetAsync(H0 + (size_t)N * HID, 0, HID * 2, stream);   // pad row G[N] = 0

  k_convW<<<(IN_DIM * HID + 255) / 256, 256, 0, stream>>>(W1, W1T, IN_DIM);
  k_convW<<<(HID * HID + 255) / 256, 256, 0, stream>>>(W2, W2T, HID);

  k_count<<<(E + 1023) / 1024, 256, 0, stream>>>(dst, cnt, pos, E);
  int nch = (N + 1023) >> 10;
  k_scan_partial<<<nch, 256, 0, stream>>>(cnt, partials, N);
  k_scan_combine<<<1, 128, 0, stream>>>(partials, rowptr, nch, N);
  k_scan_final<<<nch, 256, 0, stream>>>(cnt, partials, rowptr, N);
  k_dinv<<<(N + 255) / 256, 256, 0, stream>>>(cnt, dinv, N);
  k_fill<<<(CSRCAP + 1023) / 1024, 256, 0, stream>>>(srcs, N, CSRCAP);
  k_scatter<<<(E + 2047) / 2048, 256, 0, stream>>>(src, dst, pos, rowptr, srcs, E);

  k_gemm1<<<(N + 127) / 128, 256, 0, stream>>>(x, W1T, dinv, H0, N);
  k_agg<<<(N + 3) / 4, 256, 0, stream>>>((const uint*)H0, srcs, rowptr, dinv, b1,
                                         (uint*)H1, N);
  k_gemm2<<<(N + 127) / 128, 256, 0, stream>>>(H1, W2T, dinv, H0, N);
  k_agg_final<<<(N + 3) / 4, 256, 0, stream>>>((const uint*)H0, srcs, rowptr, dinv, b2,
                                               Wc, bc, out, N);
}

// Round 10
// 565.746 us; speedup vs baseline: 1.0757x; 1.0380x over previous
//
#include <hip/hip_runtime.h>
#include <hip/hip_bf16.h>

#define IN_DIM 768
#define HID 128
#define NC 7

typedef __attribute__((ext_vector_type(8))) short bf16x8;
typedef __attribute__((ext_vector_type(4))) float f32x4;

__device__ __forceinline__ ushort f2bf(float f) {
  uint u = __float_as_uint(f);
  u += 0x7fffu + ((u >> 16) & 1u);   // round-to-nearest-even
  return (ushort)(u >> 16);
}
__device__ __forceinline__ float lof(uint v) { return __uint_as_float(v << 16); }
__device__ __forceinline__ float hif(uint v) { return __uint_as_float(v & 0xffff0000u); }
__device__ __forceinline__ uint cvtpk(float lo, float hi) {
  uint r;
  asm("v_cvt_pk_bf16_f32 %0, %1, %2" : "=v"(r) : "v"(lo), "v"(hi));
  return r;
}

// ---------------- CSR build (r6/r9-proven) ----------------

__global__ __launch_bounds__(256) void k_count(const int* __restrict__ dst,
                                               int* __restrict__ cnt,
                                               int* __restrict__ pos, int E) {
  int e0 = (blockIdx.x * 256 + threadIdx.x) * 4;
  if (e0 + 4 <= E) {
    int4 d = *(const int4*)&dst[e0];
    int4 p;
    p.x = atomicAdd(&cnt[d.x], 1);
    p.y = atomicAdd(&cnt[d.y], 1);
    p.z = atomicAdd(&cnt[d.z], 1);
    p.w = atomicAdd(&cnt[d.w], 1);
    *(int4*)&pos[e0] = p;
  } else {
    for (int e = e0; e < E; ++e) pos[e] = atomicAdd(&cnt[dst[e]], 1);
  }
}

__device__ __forceinline__ int pad4(int c) { return (c + 3) & ~3; }

__global__ void k_scan_partial(const int* __restrict__ cnt, int* __restrict__ partials, int N) {
  __shared__ int sm[256];
  int b = blockIdx.x, t = threadIdx.x;
  int base = b * 1024 + t * 4;
  int s = 0;
  #pragma unroll
  for (int j = 0; j < 4; ++j) if (base + j < N) s += pad4(cnt[base + j]);
  sm[t] = s;
  __syncthreads();
  for (int off = 128; off > 0; off >>= 1) {
    if (t < off) sm[t] += sm[t + off];
    __syncthreads();
  }
  if (t == 0) partials[b] = sm[0];
}

__global__ void k_scan_combine(int* __restrict__ partials, int* __restrict__ rowptr,
                               int nch, int N) {
  __shared__ int sm[128];
  int t = threadIdx.x;
  int v0 = (t < nch) ? partials[t] : 0;
  sm[t] = v0;
  __syncthreads();
  for (int off = 1; off < 128; off <<= 1) {
    int add = (t >= off) ? sm[t - off] : 0;
    __syncthreads();
    sm[t] += add;
    __syncthreads();
  }
  if (t < nch) partials[t] = sm[t] - v0;
  if (t == 0) rowptr[N] = sm[127];
}

__global__ void k_scan_final(const int* __restrict__ cnt, const int* __restrict__ chunkoff,
                             int* __restrict__ rowptr, int N) {
  __shared__ int sm[256];
  int b = blockIdx.x, t = threadIdx.x;
  int base = b * 1024 + t * 4;
  int v[4]; int s = 0;
  #pragma unroll
  for (int j = 0; j < 4; ++j) { v[j] = (base + j < N) ? pad4(cnt[base + j]) : 0; s += v[j]; }
  sm[t] = s;
  __syncthreads();
  for (int off = 1; off < 256; off <<= 1) {
    int add = (t >= off) ? sm[t - off] : 0;
    __syncthreads();
    sm[t] += add;
    __syncthreads();
  }
  int excl = sm[t] - s;
  int run = chunkoff[b] + excl;
  #pragma unroll
  for (int j = 0; j < 4; ++j) {
    if (base + j < N) rowptr[base + j] = run;
    run += v[j];
  }
}

__global__ void k_dinv(const int* __restrict__ cnt, float* __restrict__ dinv, int N) {
  int n = blockIdx.x * 256 + threadIdx.x;
  if (n < N) dinv[n] = rsqrtf((float)(cnt[n] + 1));
}

// ---------------- weight convert/transpose (r6-proven) ----------------
__global__ void k_convW(const float* __restrict__ W, ushort* __restrict__ WT, int K) {
  int i = blockIdx.x * 256 + threadIdx.x;
  if (i >= K * HID) return;
  int k = i >> 7, c = i & 127;
  WT[c * K + k] = f2bf(W[i]);
}

// ---------------- device bodies for the mega kernel ----------------

// gemm1 body: x[N,768] f32 @ WT[128,768] -> G = dinv*(x@W1) bf16.
// Verbatim r9 k_gemm1 with blockIdx.x -> b, lB passed in.
__device__ __forceinline__
void gemm1_body(ushort (*lB)[128 * 64],
                const float* __restrict__ A, const ushort* __restrict__ WT,
                const float* __restrict__ dinv, ushort* __restrict__ G,
                const int N, int b) {
  const int tid = threadIdx.x;
  const int lane = tid & 63;
  const int wid = tid >> 6;                    // 0..3
  const int lr = lane & 15, lq = lane >> 4;    // lq 0..3
  const int rb = b * 128 + wid * 16;           // half-0 row base for this wave
  int ar0 = rb + lr;      if (ar0 > N - 1) ar0 = N - 1;
  int ar1 = rb + 64 + lr; if (ar1 > N - 1) ar1 = N - 1;
  const float* Ap0 = A + (size_t)ar0 * IN_DIM + lq * 8;
  const float* Ap1 = A + (size_t)ar1 * IN_DIM + lq * 8;

  auto stageB = [&](int buf, int k0) {
    #pragma unroll
    for (int j = 0; j < 4; ++j) {
      int i = j * 256 + tid;
      int r = i >> 3;
      int c = ((i & 7) ^ (r & 7)) * 8;
      __builtin_amdgcn_global_load_lds((const uint*)(WT + (size_t)r * IN_DIM + k0 + c),
                                       (uint*)&lB[buf][i * 8], 16, 0, 0);
    }
  };

  float4 fa0[4], fa1[4];
  auto loadA = [&](int k0) {
    const float* p0 = Ap0 + k0;
    fa0[0] = *(const float4*)p0;
    fa0[1] = *(const float4*)(p0 + 4);
    fa0[2] = *(const float4*)(p0 + 32);
    fa0[3] = *(const float4*)(p0 + 36);
    const float* p1 = Ap1 + k0;
    fa1[0] = *(const float4*)p1;
    fa1[1] = *(const float4*)(p1 + 4);
    fa1[2] = *(const float4*)(p1 + 32);
    fa1[3] = *(const float4*)(p1 + 36);
  };

  f32x4 acc0[8], acc1[8];
  #pragma unroll
  for (int n = 0; n < 8; ++n) {
    acc0[n] = (f32x4){0.f, 0.f, 0.f, 0.f};
    acc1[n] = (f32x4){0.f, 0.f, 0.f, 0.f};
  }

  loadA(0);
  stageB(0, 0);
  __syncthreads();

  constexpr int NT = IN_DIM / 64;
  for (int t = 0; t < NT; ++t) {
    const int cur = t & 1;
    bf16x8 av0[2], av1[2];
    {
      uint* u = (uint*)&av0[0];
      u[0] = cvtpk(fa0[0].x, fa0[0].y); u[1] = cvtpk(fa0[0].z, fa0[0].w);
      u[2] = cvtpk(fa0[1].x, fa0[1].y); u[3] = cvtpk(fa0[1].z, fa0[1].w);
      u[4] = cvtpk(fa0[2].x, fa0[2].y); u[5] = cvtpk(fa0[2].z, fa0[2].w);
      u[6] = cvtpk(fa0[3].x, fa0[3].y); u[7] = cvtpk(fa0[3].z, fa0[3].w);
      uint* v = (uint*)&av1[0];
      v[0] = cvtpk(fa1[0].x, fa1[0].y); v[1] = cvtpk(fa1[0].z, fa1[0].w);
      v[2] = cvtpk(fa1[1].x, fa1[1].y); v[3] = cvtpk(fa1[1].z, fa1[1].w);
      v[4] = cvtpk(fa1[2].x, fa1[2].y); v[5] = cvtpk(fa1[2].z, fa1[2].w);
      v[6] = cvtpk(fa1[3].x, fa1[3].y); v[7] = cvtpk(fa1[3].z, fa1[3].w);
    }
    if (t + 1 < NT) { loadA((t + 1) * 64); stageB(cur ^ 1, (t + 1) * 64); }
    #pragma unroll
    for (int kk = 0; kk < 2; ++kk) {
      #pragma unroll
      for (int n = 0; n < 8; ++n) {
        int C = n * 16 + lr;
        int slot = (kk * 4 + lq) ^ (C & 7);
        bf16x8 bv = *(const bf16x8*)&lB[cur][C * 64 + slot * 8];
        acc0[n] = __builtin_amdgcn_mfma_f32_16x16x32_bf16(av0[kk], bv, acc0[n], 0, 0, 0);
        acc1[n] = __builtin_amdgcn_mfma_f32_16x16x32_bf16(av1[kk], bv, acc1[n], 0, 0, 0);
      }
    }
    __syncthreads();
  }

  #pragma unroll
  for (int i = 0; i < 4; ++i) {
    int row0 = rb + lq * 4 + i;
    int row1 = rb + 64 + lq * 4 + i;
    float dv0 = (row0 < N) ? dinv[row0] : 0.f;
    float dv1 = (row1 < N) ? dinv[row1] : 0.f;
    #pragma unroll
    for (int n = 0; n < 8; ++n) {
      if (row0 < N) G[(size_t)row0 * HID + n * 16 + lr] = f2bf(dv0 * acc0[n][i]);
      if (row1 < N) G[(size_t)row1 * HID + n * 16 + lr] = f2bf(dv1 * acc1[n][i]);
    }
  }
}

// scatter body (verbatim r9 with blockIdx.x -> b)
__device__ __forceinline__
void scatter_body(const int* __restrict__ src, const int* __restrict__ dst,
                  const int* __restrict__ pos, const int* __restrict__ rowptr,
                  int* __restrict__ srcs, int E, int b) {
  int e0 = (b * 256 + threadIdx.x) * 8;
  if (e0 + 8 <= E) {
    int s[8], d[8], p[8];
    *(int4*)&s[0] = *(const int4*)&src[e0];
    *(int4*)&s[4] = *(const int4*)&src[e0 + 4];
    *(int4*)&d[0] = *(const int4*)&dst[e0];
    *(int4*)&d[4] = *(const int4*)&dst[e0 + 4];
    *(int4*)&p[0] = *(const int4*)&pos[e0];
    *(int4*)&p[4] = *(const int4*)&pos[e0 + 4];
    int rp[8];
    #pragma unroll
    for (int j = 0; j < 8; ++j) rp[j] = rowptr[d[j]];
    #pragma unroll
    for (int j = 0; j < 8; ++j) srcs[rp[j] + p[j]] = s[j];
  } else {
    for (int e = e0; e < E; ++e) srcs[rowptr[dst[e]] + pos[e]] = src[e];
  }
}

// pad-fill body: write only the <=3 pad slots per row (src = N, G[N] = 0)
__device__ __forceinline__
void fillpad_body(const int* __restrict__ cnt, const int* __restrict__ rowptr,
                  int* __restrict__ srcs, int N, int b) {
  int n = b * 256 + threadIdx.x;
  if (n < N) {
    int c = cnt[n];
    int e0 = rowptr[n] + c;
    int e1 = rowptr[n] + pad4(c);
    for (int i = e0; i < e1; ++i) srcs[i] = N;
  }
}

// mega kernel: 7-slot role pattern per group — 2x gemm1, 4x scatter, 1x fillpad
__global__ __launch_bounds__(256)
void k_mega(const float* __restrict__ A, const ushort* __restrict__ WT,
            const float* __restrict__ dinv, ushort* __restrict__ G, int N,
            const int* __restrict__ src, const int* __restrict__ dst,
            const int* __restrict__ pos, const int* __restrict__ rowptr,
            int* __restrict__ srcs, int E, const int* __restrict__ cnt,
            int Gg1, int Gsc, int Gfp) {
  __shared__ ushort lB[2][128 * 64];
  int grp = blockIdx.x / 7, slot = blockIdx.x % 7;
  if (slot < 2) {
    int b = grp * 2 + slot;
    if (b < Gg1) gemm1_body(lB, A, WT, dinv, G, N, b);
  } else if (slot < 6) {
    int b = grp * 4 + (slot - 2);
    if (b < Gsc) scatter_body(src, dst, pos, rowptr, srcs, E, b);
  } else {
    if (grp < Gfp) fillpad_body(cnt, rowptr, srcs, N, grp);
  }
}

// ---------------- GEMM2: H1[N,128] bf16 @ WT[128,128] -> G = dinv*(H1@W2), bf16 ----------------
__global__ __launch_bounds__(256)
void k_gemm2(const ushort* __restrict__ A, const ushort* __restrict__ WT,
             const float* __restrict__ dinv, ushort* __restrict__ G, const int N) {
  __shared__ ushort lA[2][128 * 64];
  __shared__ ushort lB[2][128 * 64];
  const int tid = threadIdx.x;
  const int lane = tid & 63;
  const int wid = tid >> 6;
  const int wm = wid >> 1, wn = wid & 1;
  const int row0 = blockIdx.x * 128;
  const int lr = lane & 15;
  const int lk8 = lane >> 4;
  constexpr int K = HID;

  auto stage = [&](int buf, int k0) {
    #pragma unroll
    for (int j = 0; j < 4; ++j) {
      int i = j * 256 + tid;
      int r = i >> 3;
      int c = ((i & 7) ^ (r & 7)) * 8;
      int ga = row0 + r; ga = ga < N ? ga : N - 1;
      __builtin_amdgcn_global_load_lds((const uint*)(A + (size_t)ga * K + k0 + c),
                                       (uint*)&lA[buf][i * 8], 16, 0, 0);
      __builtin_amdgcn_global_load_lds((const uint*)(WT + (size_t)r * K + k0 + c),
                                       (uint*)&lB[buf][i * 8], 16, 0, 0);
    }
  };

  f32x4 acc[4][4];
  #pragma unroll
  for (int m = 0; m < 4; ++m)
    #pragma unroll
    for (int n = 0; n < 4; ++n)
      acc[m][n] = (f32x4){0.f, 0.f, 0.f, 0.f};

  constexpr int NT = K / 64;
  stage(0, 0);
  __syncthreads();

  for (int t = 0; t < NT; ++t) {
    const int cur = t & 1;
    if (t + 1 < NT) stage(cur ^ 1, (t + 1) * 64);
    #pragma unroll
    for (int kk = 0; kk < 2; ++kk) {
      bf16x8 av[4], bv[4];
      #pragma unroll
      for (int m = 0; m < 4; ++m) {
        int R = wm * 64 + m * 16 + lr;
        int slot = (kk * 4 + lk8) ^ (R & 7);
        av[m] = *(const bf16x8*)&lA[cur][R * 64 + slot * 8];
      }
      #pragma unroll
      for (int n = 0; n < 4; ++n) {
        int C = wn * 64 + n * 16 + lr;
        int slot = (kk * 4 + lk8) ^ (C & 7);
        bv[n] = *(const bf16x8*)&lB[cur][C * 64 + slot * 8];
      }
      #pragma unroll
      for (int m = 0; m < 4; ++m)
        #pragma unroll
        for (int n = 0; n < 4; ++n)
          acc[m][n] = __builtin_amdgcn_mfma_f32_16x16x32_bf16(av[m], bv[n], acc[m][n], 0, 0, 0);
    }
    __syncthreads();
  }

  #pragma unroll
  for (int m = 0; m < 4; ++m) {
    #pragma unroll
    for (int i = 0; i < 4; ++i) {
      int row = row0 + wm * 64 + m * 16 + (lane >> 4) * 4 + i;
      if (row < N) {
        float dv = dinv[row];
        #pragma unroll
        for (int n = 0; n < 4; ++n) {
          int col = wn * 64 + n * 16 + lr;
          G[(size_t)row * HID + col] = f2bf(dv * acc[m][n][i]);
        }
      }
    }
  }
}

// ---------------- aggregation: full-row gathers, 32-deep pipeline (r6-proven) ----------------
// G rows pre-scaled by dinv[src]; pad src = N with G[N] = 0.

#define GL(v, s) uint v = Gp[(size_t)(s) * 64 + lane];
#define AC(v) { a0 += lof(v); a1 += hif(v); }

__device__ __forceinline__ void agg32(const uint* __restrict__ Gp,
                                      const int* __restrict__ srcs,
                                      int i, int lane, float& a0, float& a1) {
  int4 sa = *(const int4*)&srcs[i];
  int4 sb = *(const int4*)&srcs[i + 4];
  int4 sc = *(const int4*)&srcs[i + 8];
  int4 sd = *(const int4*)&srcs[i + 12];
  int4 se = *(const int4*)&srcs[i + 16];
  int4 sf = *(const int4*)&srcs[i + 20];
  int4 sg = *(const int4*)&srcs[i + 24];
  int4 sh = *(const int4*)&srcs[i + 28];
  GL(h00, sa.x) GL(h01, sa.y) GL(h02, sa.z) GL(h03, sa.w)
  GL(h04, sb.x) GL(h05, sb.y) GL(h06, sb.z) GL(h07, sb.w)
  GL(h08, sc.x) GL(h09, sc.y) GL(h10, sc.z) GL(h11, sc.w)
  GL(h12, sd.x) GL(h13, sd.y) GL(h14, sd.z) GL(h15, sd.w)
  GL(h16, se.x) GL(h17, se.y) GL(h18, se.z) GL(h19, se.w)
  GL(h20, sf.x) GL(h21, sf.y) GL(h22, sf.z) GL(h23, sf.w)
  GL(h24, sg.x) GL(h25, sg.y) GL(h26, sg.z) GL(h27, sg.w)
  GL(h28, sh.x) GL(h29, sh.y) GL(h30, sh.z) GL(h31, sh.w)
  __builtin_amdgcn_sched_barrier(0);
  AC(h00) AC(h01) AC(h02) AC(h03) AC(h04) AC(h05) AC(h06) AC(h07)
  AC(h08) AC(h09) AC(h10) AC(h11) AC(h12) AC(h13) AC(h14) AC(h15)
  AC(h16) AC(h17) AC(h18) AC(h19) AC(h20) AC(h21) AC(h22) AC(h23)
  AC(h24) AC(h25) AC(h26) AC(h27) AC(h28) AC(h29) AC(h30) AC(h31)
}

__device__ __forceinline__ void agg16(const uint* __restrict__ Gp,
                                      const int* __restrict__ srcs,
                                      int i, int lane, float& a0, float& a1) {
  int4 sa = *(const int4*)&srcs[i];
  int4 sb = *(const int4*)&srcs[i + 4];
  int4 sc = *(const int4*)&srcs[i + 8];
  int4 sd = *(const int4*)&srcs[i + 12];
  GL(h00, sa.x) GL(h01, sa.y) GL(h02, sa.z) GL(h03, sa.w)
  GL(h04, sb.x) GL(h05, sb.y) GL(h06, sb.z) GL(h07, sb.w)
  GL(h08, sc.x) GL(h09, sc.y) GL(h10, sc.z) GL(h11, sc.w)
  GL(h12, sd.x) GL(h13, sd.y) GL(h14, sd.z) GL(h15, sd.w)
  __builtin_amdgcn_sched_barrier(0);
  AC(h00) AC(h01) AC(h02) AC(h03) AC(h04) AC(h05) AC(h06) AC(h07)
  AC(h08) AC(h09) AC(h10) AC(h11) AC(h12) AC(h13) AC(h14) AC(h15)
}

__device__ __forceinline__ void agg4(const uint* __restrict__ Gp,
                                     const int* __restrict__ srcs,
                                     int i, int lane, float& a0, float& a1) {
  int4 sa = *(const int4*)&srcs[i];
  GL(h00, sa.x) GL(h01, sa.y) GL(h02, sa.z) GL(h03, sa.w)
  __builtin_amdgcn_sched_barrier(0);
  AC(h00) AC(h01) AC(h02) AC(h03)
}

__global__ __launch_bounds__(256)
void k_agg(const uint* __restrict__ Gp, const int* __restrict__ srcs,
           const int* __restrict__ rowptr, const float* __restrict__ dinv,
           const float* __restrict__ bias, uint* __restrict__ Ou, int N) {
  int w = (blockIdx.x * 256 + threadIdx.x) >> 6;
  if (w >= N) return;
  int lane = threadIdx.x & 63;
  int start = rowptr[w], end = rowptr[w + 1];
  float di = dinv[w];
  uint hv = Gp[(size_t)w * 64 + lane];
  float a0 = lof(hv), a1 = hif(hv);
  int i = start;
  for (; i + 32 <= end; i += 32) agg32(Gp, srcs, i, lane, a0, a1);
  for (; i + 16 <= end; i += 16) agg16(Gp, srcs, i, lane, a0, a1);
  for (; i < end; i += 4)        agg4(Gp, srcs, i, lane, a0, a1);
  float2 bb = ((const float2*)bias)[lane];
  a0 = fmaxf(fmaf(di, a0, bb.x), 0.f);
  a1 = fmaxf(fmaf(di, a1, bb.y), 0.f);
  Ou[(size_t)w * 64 + lane] = (uint)f2bf(a0) | ((uint)f2bf(a1) << 16);
}

__global__ __launch_bounds__(256)
void k_agg_final(const uint* __restrict__ Gp, const int* __restrict__ srcs,
                 const int* __restrict__ rowptr, const float* __restrict__ dinv,
                 const float* __restrict__ bias, const float* __restrict__ Wc,
                 const float* __restrict__ bc, float* __restrict__ out, int N) {
  int w = (blockIdx.x * 256 + threadIdx.x) >> 6;
  if (w >= N) return;
  int lane = threadIdx.x & 63;
  int start = rowptr[w], end = rowptr[w + 1];
  float di = dinv[w];
  uint hv = Gp[(size_t)w * 64 + lane];
  float a0 = lof(hv), a1 = hif(hv);
  int i = start;
  for (; i + 32 <= end; i += 32) agg32(Gp, srcs, i, lane, a0, a1);
  for (; i + 16 <= end; i += 16) agg16(Gp, srcs, i, lane, a0, a1);
  for (; i < end; i += 4)        agg4(Gp, srcs, i, lane, a0, a1);
  float2 bb = ((const float2*)bias)[lane];
  a0 = fmaxf(fmaf(di, a0, bb.x), 0.f);
  a1 = fmaxf(fmaf(di, a1, bb.y), 0.f);
  const float* w0 = &Wc[(2 * lane) * NC];
  #pragma unroll
  for (int c = 0; c < NC; ++c) {
    float s = a0 * w0[c] + a1 * w0[NC + c];
    #pragma unroll
    for (int off = 32; off > 0; off >>= 1) s += __shfl_xor(s, off, 64);
    if (lane == 0) out[(size_t)w * NC + c] = s + bc[c];
  }
}

extern "C" void kernel_launch(void* const* d_in, const int* in_sizes, int n_in,
                              void* d_out, int out_size, void* d_ws, size_t ws_size,
                              hipStream_t stream) {
  const float* x  = (const float*)d_in[0];
  const int*   ei = (const int*)d_in[1];
  const float* W1 = (const float*)d_in[2];
  const float* b1 = (const float*)d_in[3];
  const float* W2 = (const float*)d_in[4];
  const float* b2 = (const float*)d_in[5];
  const float* Wc = (const float*)d_in[6];
  const float* bc = (const float*)d_in[7];
  float* out = (float*)d_out;

  const int N = in_sizes[0] / IN_DIM;
  const int E = in_sizes[1] / 2;
  const int* src = ei;
  const int* dst = ei + E;
  const int CSRCAP = E + 3 * N + 64;

  char* ws = (char*)d_ws;
  size_t off = 0;
  auto alloc = [&](size_t bytes) -> void* {
    off = (off + 255) & ~(size_t)255;
    void* p = ws + off;
    off += bytes;
    return p;
  };
  ushort* H0     = (ushort*)alloc((size_t)(N + 1) * HID * 2);  // G buffers (row N = pad = 0)
  ushort* H1     = (ushort*)alloc((size_t)(N + 1) * HID * 2);
  int*    srcs   = (int*)alloc((size_t)CSRCAP * 4);
  int*    cnt    = (int*)alloc((size_t)N * 4);
  int*    pos    = (int*)alloc((size_t)E * 4);
  int*    rowptr = (int*)alloc((size_t)(N + 1) * 4);
  float*  dinv   = (float*)alloc((size_t)N * 4);
  int*    partials = (int*)alloc(512);
  ushort* W1T    = (ushort*)alloc((size_t)IN_DIM * HID * 2);
  ushort* W2T    = (ushort*)alloc((size_t)HID * HID * 2);

  hipMemsetAsync(cnt, 0, (size_t)N * 4, stream);
  hipMemsetAsync(H0 + (size_t)N * HID, 0, HID * 2, stream);   // pad row G[N] = 0

  k_convW<<<(IN_DIM * HID + 255) / 256, 256, 0, stream>>>(W1, W1T, IN_DIM);
  k_convW<<<(HID * HID + 255) / 256, 256, 0, stream>>>(W2, W2T, HID);

  k_count<<<(E + 1023) / 1024, 256, 0, stream>>>(dst, cnt, pos, E);
  int nch = (N + 1023) >> 10;
  k_scan_partial<<<nch, 256, 0, stream>>>(cnt, partials, N);
  k_scan_combine<<<1, 128, 0, stream>>>(partials, rowptr, nch, N);
  k_scan_final<<<nch, 256, 0, stream>>>(cnt, partials, rowptr, N);
  k_dinv<<<(N + 255) / 256, 256, 0, stream>>>(cnt, dinv, N);

  // mega: gemm1 || scatter || pad-fill (7-slot role pattern: 2/4/1)
  const int Gg1 = (N + 127) / 128;
  const int Gsc = (E + 2047) / 2048;
  const int Gfp = (N + 255) / 256;
  int ngroups = (Gg1 + 1) / 2;
  if ((Gsc + 3) / 4 > ngroups) ngroups = (Gsc + 3) / 4;
  if (Gfp > ngroups) ngroups = Gfp;
  k_mega<<<ngroups * 7, 256, 0, stream>>>(x, W1T, dinv, H0, N,
                                          src, dst, pos, rowptr, srcs, E, cnt,
                                          Gg1, Gsc, Gfp);

  k_agg<<<(N + 3) / 4, 256, 0, stream>>>((const uint*)H0, srcs, rowptr, dinv, b1,
                                         (uint*)H1, N);
  k_gemm2<<<(N + 127) / 128, 256, 0, stream>>>(H1, W2T, dinv, H0, N);
  k_agg_final<<<(N + 3) / 4, 256, 0, stream>>>((const uint*)H0, srcs, rowptr, dinv, b2,
                                               Wc, bc, out, N);
}